// Round 8
// baseline (116.967 us; speedup 1.0000x reference)
//
#include <hip/hip_runtime.h>

#define NRAYS 8192
#define NS    256
#define HID   64
#define RPB   16     // rays per block: 4 waves x 4 quarter-waves
#define SPT   16     // samples per thread (16 lanes cover 256 samples)

typedef float v2f __attribute__((ext_vector_type(2)));
static __device__ __forceinline__ v2f splat2(float s) { v2f v; v.x = s; v.y = s; return v; }

// guaranteed VOP3P packed fp32 fma: d = a*b + c
static __device__ __forceinline__ v2f pk_fma(v2f a, v2f b, v2f c) {
    v2f d;
    asm("v_pk_fma_f32 %0, %1, %2, %3" : "=v"(d) : "v"(a), "v"(b), "v"(c));
    return d;
}
static __device__ __forceinline__ void pk_fma_acc(v2f& acc, v2f a, v2f b) {
    asm("v_pk_fma_f32 %0, %1, %2, %0" : "+v"(acc) : "v"(a), "v"(b));
}

__global__ __launch_bounds__(256) void vr_kernel(
    const float* __restrict__ ray_start,
    const float* __restrict__ ray_dir,
    const float* __restrict__ sampled_depth,
    const float* __restrict__ sampled_dists,
    const int*   __restrict__ sampled_idx,
    const float* __restrict__ W1,
    const float* __restrict__ b1,
    const float* __restrict__ w_sigma,
    const float* __restrict__ W_rgb,
    const float* __restrict__ W_dir,
    const float* __restrict__ b_rgb,
    float* __restrict__ out)
{
    // sW[h]     = {w_sigma[h], W_rgb[h][0], W_rgb[h][1], W_rgb[h][2]}  (block-shared)
    // sAB[r][h] = {A, B} with hv(h,d) = relu(A + d*B)                  (per-ray)
    __shared__ float4 sW[HID];
    __shared__ float2 sAB[RPB][HID];

    const int t = threadIdx.x;
    if (t < HID)
        sW[t] = make_float4(w_sigma[t], W_rgb[t*3+0], W_rgb[t*3+1], W_rgb[t*3+2]);

#pragma unroll
    for (int p = 0; p < 4; ++p) {
        const int idx = t + p * 256;        // 1024 (ray,h) pairs
        const int r   = idx >> 6;
        const int h   = idx & 63;
        const int ray = blockIdx.x * RPB + r;
        const float ox = ray_start[ray*3+0], oy = ray_start[ray*3+1], oz = ray_start[ray*3+2];
        const float dx = ray_dir[ray*3+0],  dy = ray_dir[ray*3+1],  dz = ray_dir[ray*3+2];
        const float w0 = W1[h], w1 = W1[HID + h], w2 = W1[2*HID + h];
        const float A = fmaf(w0, ox, fmaf(w1, oy, fmaf(w2, oz, b1[h])));
        const float B = fmaf(w0, dx, fmaf(w1, dy, w2 * dz));
        sAB[r][h] = make_float2(A, B);
    }
    __syncthreads();

    const int lane = t & 63;
    const int wv   = t >> 6;
    const int ql   = lane & 15;                 // position within quarter-wave
    const int rs   = wv * 4 + (lane >> 4);      // ray slot in block
    const int ray  = blockIdx.x * RPB + rs;

    // per-ray view-dependent rgb bias (uniform across the quarter-wave)
    const float dx = ray_dir[ray*3+0], dy = ray_dir[ray*3+1], dz = ray_dir[ray*3+2];
    const float dwr = fmaf(dx, W_dir[0], fmaf(dy, W_dir[3], fmaf(dz, W_dir[6], b_rgb[0])));
    const float dwg = fmaf(dx, W_dir[1], fmaf(dy, W_dir[4], fmaf(dz, W_dir[7], b_rgb[1])));
    const float dwb = fmaf(dx, W_dir[2], fmaf(dy, W_dir[5], fmaf(dz, W_dir[8], b_rgb[2])));

    // this thread owns samples SPT*ql .. SPT*ql+15 (contiguous)
    const size_t rbase = (size_t)ray * NS + (size_t)ql * SPT;
    float dpt[SPT], dsv[SPT];
    int   vid[SPT];
#pragma unroll
    for (int i = 0; i < 4; ++i) {
        const float4 d4 = ((const float4*)(sampled_depth + rbase))[i];
        const float4 s4 = ((const float4*)(sampled_dists + rbase))[i];
        const int4   i4 = ((const int4*)(sampled_idx + rbase))[i];
        dpt[4*i+0] = d4.x; dpt[4*i+1] = d4.y; dpt[4*i+2] = d4.z; dpt[4*i+3] = d4.w;
        dsv[4*i+0] = s4.x; dsv[4*i+1] = s4.y; dsv[4*i+2] = s4.z; dsv[4*i+3] = s4.w;
        vid[4*i+0] = i4.x; vid[4*i+1] = i4.y; vid[4*i+2] = i4.z; vid[4*i+3] = i4.w;
    }

    v2f d2[8];
#pragma unroll
    for (int i = 0; i < 8; ++i) { d2[i].x = dpt[2*i]; d2[i].y = dpt[2*i+1]; }

    const v2f zero2 = splat2(0.f);
    v2f sg2[8], cr2[8], cg2[8], cb2[8];
#pragma unroll
    for (int i = 0; i < 8; ++i) { sg2[i] = zero2; cr2[i] = zero2; cg2[i] = zero2; cb2[i] = zero2; }

#pragma unroll 8
    for (int h = 0; h < HID; ++h) {
        const float4 w  = sW[h];           // ds_read_b128, broadcast
        const float2 ab = sAB[rs][h];      // ds_read_b64, 4 addrs/wave
        const v2f a2  = splat2(ab.x);
        const v2f b2  = splat2(ab.y);
        const v2f ws2 = splat2(w.x);
        const v2f wr2 = splat2(w.y);
        const v2f wg2 = splat2(w.z);
        const v2f wq2 = splat2(w.w);
#pragma unroll
        for (int i = 0; i < 8; ++i) {
            v2f hv = pk_fma(b2, d2[i], a2);
            hv.x = fmaxf(hv.x, 0.f);       // relu (no pk_max_f32 on CDNA)
            hv.y = fmaxf(hv.y, 0.f);
            pk_fma_acc(sg2[i], hv, ws2);
            pk_fma_acc(cr2[i], hv, wr2);
            pk_fma_acc(cg2[i], hv, wg2);
            pk_fma_acc(cb2[i], hv, wq2);
        }
    }

    // free energy + thread-local inclusive scan over 16 samples
    float c[SPT];
    float run = 0.f;
#pragma unroll
    for (int j = 0; j < SPT; ++j) {
        const float sg = (j & 1) ? sg2[j>>1].y : sg2[j>>1].x;
        float f = fmaxf(sg, 0.f) * dsv[j] * 7.0f;
        if (vid[j] == -1) f = 0.f;
        run += f;
        c[j] = run;
    }

    // quarter-wave (width 16) exclusive scan of per-thread totals
    float tot = run;
#pragma unroll
    for (int off = 1; off < 16; off <<= 1) {
        const float v = __shfl_up(tot, off, 16);
        if (ql >= off) tot += v;
    }
    const float base = tot - run;

    // telescoped probs: p[j] = exp(-(base+c[j-1])) - exp(-(base+c[j]))
    float Eprev = __expf(-base);
    float prob[SPT];
    float s0 = 0.f, s1 = 0.f, s2 = 0.f, s3 = 0.f, s4 = 0.f;
#pragma unroll
    for (int j = 0; j < SPT; ++j) {
        const float Ej = __expf(-(base + c[j]));
        const float p  = Eprev - Ej;
        Eprev = Ej;
        prob[j] = p;
        const float lr = (j & 1) ? cr2[j>>1].y : cr2[j>>1].x;
        const float lg = (j & 1) ? cg2[j>>1].y : cg2[j>>1].x;
        const float lb = (j & 1) ? cb2[j>>1].y : cb2[j>>1].x;
        const float rr = __builtin_amdgcn_rcpf(1.f + __expf(-(lr + dwr)));
        const float gg = __builtin_amdgcn_rcpf(1.f + __expf(-(lg + dwg)));
        const float bb = __builtin_amdgcn_rcpf(1.f + __expf(-(lb + dwb)));
        s0 += p;
        s1 = fmaf(dpt[j], p, s1);
        s2 = fmaf(rr, p, s2);
        s3 = fmaf(gg, p, s3);
        s4 = fmaf(bb, p, s4);
    }

    // quarter-wave reduction of the 5 sums
#pragma unroll
    for (int off = 8; off >= 1; off >>= 1) {
        s0 += __shfl_xor(s0, off, 16);
        s1 += __shfl_xor(s1, off, 16);
        s2 += __shfl_xor(s2, off, 16);
        s3 += __shfl_xor(s3, off, 16);
        s4 += __shfl_xor(s4, off, 16);
    }

    float* orow = out + (size_t)ray * (NS + 5);
#pragma unroll
    for (int j = 0; j < SPT; ++j)
        orow[5 + SPT*ql + j] = prob[j];

    if (ql == 0) {
        orow[0] = s2;          // r
        orow[1] = s3;          // g
        orow[2] = s4;          // b
        orow[3] = s1;          // depth
        orow[4] = 1.f - s0;    // missed
    }
}

extern "C" void kernel_launch(void* const* d_in, const int* in_sizes, int n_in,
                              void* d_out, int out_size, void* d_ws, size_t ws_size,
                              hipStream_t stream)
{
    vr_kernel<<<NRAYS / RPB, 256, 0, stream>>>(
        (const float*)d_in[0],   // ray_start
        (const float*)d_in[1],   // ray_dir
        (const float*)d_in[2],   // sampled_depth
        (const float*)d_in[3],   // sampled_dists
        (const int*)  d_in[4],   // sampled_idx
        (const float*)d_in[5],   // W1
        (const float*)d_in[6],   // b1
        (const float*)d_in[7],   // w_sigma
        (const float*)d_in[8],   // W_rgb
        (const float*)d_in[9],   // W_dir
        (const float*)d_in[10],  // b_rgb
        (float*)d_out);
}

// Round 9
// 108.244 us; speedup vs baseline: 1.0806x; 1.0806x over previous
//
#include <hip/hip_runtime.h>

#define NRAYS 8192
#define NS    256
#define HID   64
#define RPB   8      // rays per block: 4 waves x 2 half-waves
#define SPT   8      // samples per thread (32 threads cover 256 samples)

__global__ __launch_bounds__(256) void vr_kernel(
    const float* __restrict__ ray_start,
    const float* __restrict__ ray_dir,
    const float* __restrict__ sampled_depth,
    const float* __restrict__ sampled_dists,
    const int*   __restrict__ sampled_idx,
    const float* __restrict__ W1,
    const float* __restrict__ b1,
    const float* __restrict__ w_sigma,
    const float* __restrict__ W_rgb,
    const float* __restrict__ W_dir,
    const float* __restrict__ b_rgb,
    float* __restrict__ out)
{
    // sW[h]     = {w_sigma[h], W_rgb[h][0], W_rgb[h][1], W_rgb[h][2]}  (block-shared)
    // sAB[r][h] = {A, B} with hv(h,d) = relu(A + d*B)                  (per-ray)
    __shared__ float4 sW[HID];
    __shared__ float2 sAB[RPB][HID];

    const int t = threadIdx.x;
    if (t < HID)
        sW[t] = make_float4(w_sigma[t], W_rgb[t*3+0], W_rgb[t*3+1], W_rgb[t*3+2]);

#pragma unroll
    for (int p = 0; p < 2; ++p) {
        const int idx = t + p * 256;        // 512 (ray,h) pairs
        const int r   = idx >> 6;
        const int h   = idx & 63;
        const int ray = blockIdx.x * RPB + r;
        const float ox = ray_start[ray*3+0], oy = ray_start[ray*3+1], oz = ray_start[ray*3+2];
        const float dx = ray_dir[ray*3+0],  dy = ray_dir[ray*3+1],  dz = ray_dir[ray*3+2];
        const float w0 = W1[h], w1 = W1[HID + h], w2 = W1[2*HID + h];
        const float A = fmaf(w0, ox, fmaf(w1, oy, fmaf(w2, oz, b1[h])));
        const float B = fmaf(w0, dx, fmaf(w1, dy, w2 * dz));
        sAB[r][h] = make_float2(A, B);
    }
    __syncthreads();

    const int lane = t & 63;
    const int wave = t >> 6;
    const int hl   = lane & 31;                 // position within half-wave
    const int r    = wave * 2 + (lane >> 5);    // ray slot in block
    const int ray  = blockIdx.x * RPB + r;

    // per-ray view-dependent rgb bias
    const float dx = ray_dir[ray*3+0], dy = ray_dir[ray*3+1], dz = ray_dir[ray*3+2];
    const float dwr = fmaf(dx, W_dir[0], fmaf(dy, W_dir[3], fmaf(dz, W_dir[6], b_rgb[0])));
    const float dwg = fmaf(dx, W_dir[1], fmaf(dy, W_dir[4], fmaf(dz, W_dir[7], b_rgb[1])));
    const float dwb = fmaf(dx, W_dir[2], fmaf(dy, W_dir[5], fmaf(dz, W_dir[8], b_rgb[2])));

    // this thread owns samples SPT*hl .. SPT*hl+7 (contiguous)
    const size_t rbase = (size_t)ray * NS + (size_t)hl * SPT;
    const float4 dep0 = ((const float4*)(sampled_depth + rbase))[0];
    const float4 dep1 = ((const float4*)(sampled_depth + rbase))[1];
    const float4 dst0 = ((const float4*)(sampled_dists + rbase))[0];
    const float4 dst1 = ((const float4*)(sampled_dists + rbase))[1];
    const int4   vi0  = ((const int4*)(sampled_idx + rbase))[0];
    const int4   vi1  = ((const int4*)(sampled_idx + rbase))[1];

    const float dpt[SPT] = {dep0.x, dep0.y, dep0.z, dep0.w, dep1.x, dep1.y, dep1.z, dep1.w};
    const float dsv[SPT] = {dst0.x, dst0.y, dst0.z, dst0.w, dst1.x, dst1.y, dst1.z, dst1.w};
    const int   vid[SPT] = {vi0.x, vi0.y, vi0.z, vi0.w, vi1.x, vi1.y, vi1.z, vi1.w};

    float sig[SPT] = {0,0,0,0,0,0,0,0};
    float cr[SPT]  = {0,0,0,0,0,0,0,0};
    float cg[SPT]  = {0,0,0,0,0,0,0,0};
    float cb[SPT]  = {0,0,0,0,0,0,0,0};

    // unroll 2 (NOT 8): keep the loop body small enough to stay I$-resident.
    // Full unrolling produced multi-KB straight-line bodies; suspected L1I
    // thrash is the universal ~2.4x-above-floor plateau across R2..R8.
#pragma unroll 2
    for (int h = 0; h < HID; ++h) {
        const float4 w  = sW[h];
        const float2 ab = sAB[r][h];
#pragma unroll
        for (int j = 0; j < SPT; ++j) {
            const float hv = fmaxf(fmaf(ab.y, dpt[j], ab.x), 0.f);
            sig[j] = fmaf(hv, w.x, sig[j]);
            cr[j]  = fmaf(hv, w.y, cr[j]);
            cg[j]  = fmaf(hv, w.z, cg[j]);
            cb[j]  = fmaf(hv, w.w, cb[j]);
        }
    }

    // free energy + thread-local inclusive scan
    float c[SPT];
    float run = 0.f;
#pragma unroll
    for (int j = 0; j < SPT; ++j) {
        float f = fmaxf(sig[j], 0.f) * dsv[j] * 7.0f;
        if (vid[j] == -1) f = 0.f;
        run += f;
        c[j] = run;
    }

    // half-wave (width 32) exclusive scan of per-thread totals
    float tot = run;
#pragma unroll
    for (int off = 1; off < 32; off <<= 1) {
        const float v = __shfl_up(tot, off, 32);
        if (hl >= off) tot += v;
    }
    const float base = tot - run;

    // telescoped probs: p[j] = exp(-(base+c[j-1])) - exp(-(base+c[j]))
    float Eprev = __expf(-base);
    float prob[SPT];
    float s0 = 0.f, s1 = 0.f, s2 = 0.f, s3 = 0.f, s4 = 0.f;
#pragma unroll
    for (int j = 0; j < SPT; ++j) {
        const float Ej = __expf(-(base + c[j]));
        const float p  = Eprev - Ej;
        Eprev = Ej;
        prob[j] = p;
        const float rr = __builtin_amdgcn_rcpf(1.f + __expf(-(cr[j] + dwr)));
        const float gg = __builtin_amdgcn_rcpf(1.f + __expf(-(cg[j] + dwg)));
        const float bb = __builtin_amdgcn_rcpf(1.f + __expf(-(cb[j] + dwb)));
        s0 += p;
        s1 = fmaf(dpt[j], p, s1);
        s2 = fmaf(rr, p, s2);
        s3 = fmaf(gg, p, s3);
        s4 = fmaf(bb, p, s4);
    }

    // half-wave reduction of the 5 sums
#pragma unroll
    for (int off = 16; off >= 1; off >>= 1) {
        s0 += __shfl_xor(s0, off, 32);
        s1 += __shfl_xor(s1, off, 32);
        s2 += __shfl_xor(s2, off, 32);
        s3 += __shfl_xor(s3, off, 32);
        s4 += __shfl_xor(s4, off, 32);
    }

    float* orow = out + (size_t)ray * (NS + 5);
#pragma unroll
    for (int j = 0; j < SPT; ++j)
        orow[5 + SPT*hl + j] = prob[j];

    if (hl == 0) {
        orow[0] = s2;          // r
        orow[1] = s3;          // g
        orow[2] = s4;          // b
        orow[3] = s1;          // depth
        orow[4] = 1.f - s0;    // missed
    }
}

extern "C" void kernel_launch(void* const* d_in, const int* in_sizes, int n_in,
                              void* d_out, int out_size, void* d_ws, size_t ws_size,
                              hipStream_t stream)
{
    vr_kernel<<<NRAYS / RPB, 256, 0, stream>>>(
        (const float*)d_in[0],   // ray_start
        (const float*)d_in[1],   // ray_dir
        (const float*)d_in[2],   // sampled_depth
        (const float*)d_in[3],   // sampled_dists
        (const int*)  d_in[4],   // sampled_idx
        (const float*)d_in[5],   // W1
        (const float*)d_in[6],   // b1
        (const float*)d_in[7],   // w_sigma
        (const float*)d_in[8],   // W_rgb
        (const float*)d_in[9],   // W_dir
        (const float*)d_in[10],  // b_rgb
        (float*)d_out);
}

// Round 10
// 104.034 us; speedup vs baseline: 1.1243x; 1.0405x over previous
//
#include <hip/hip_runtime.h>

#define NRAYS 8192
#define NS    256
#define HID   64
#define NPAIR 32     // hidden-unit pairs
#define RPB   8      // rays per block: 4 waves x 2 half-waves
#define SPT   8      // samples per thread (32 threads cover 256 samples)

typedef _Float16 f16x2 __attribute__((ext_vector_type(2)));

static __device__ __forceinline__ float fdot2(f16x2 a, f16x2 b, float c) {
    return __builtin_amdgcn_fdot2(a, b, c, false);   // v_dot2_f32_f16
}
static __device__ __forceinline__ f16x2 mk2(float a, float b) {
    f16x2 v; v.x = (_Float16)a; v.y = (_Float16)b; return v;
}

struct __align__(16) W4  { f16x2 ws, wr, wg, wb; };  // 16 B -> ds_read_b128
struct __align__(8)  AB2 { f16x2 A, B; };            //  8 B -> ds_read_b64

__global__ __launch_bounds__(256) void vr_kernel(
    const float* __restrict__ ray_start,
    const float* __restrict__ ray_dir,
    const float* __restrict__ sampled_depth,
    const float* __restrict__ sampled_dists,
    const int*   __restrict__ sampled_idx,
    const float* __restrict__ W1,
    const float* __restrict__ b1,
    const float* __restrict__ w_sigma,
    const float* __restrict__ W_rgb,
    const float* __restrict__ W_dir,
    const float* __restrict__ b_rgb,
    float* __restrict__ out)
{
    // sW[k]     : f16 pairs {w_sigma, W_rgb[:,0..2]} for hidden units 2k,2k+1
    // sAB[r][k] : f16 pairs {A,B}, hv(h,d) = relu(A + d*B)
    __shared__ W4  sW[NPAIR];
    __shared__ AB2 sAB[RPB][NPAIR];

    const int t = threadIdx.x;
    if (t < NPAIR) {
        const int h0 = 2*t, h1 = 2*t + 1;
        W4 w;
        w.ws = mk2(w_sigma[h0],    w_sigma[h1]);
        w.wr = mk2(W_rgb[h0*3+0],  W_rgb[h1*3+0]);
        w.wg = mk2(W_rgb[h0*3+1],  W_rgb[h1*3+1]);
        w.wb = mk2(W_rgb[h0*3+2],  W_rgb[h1*3+2]);
        sW[t] = w;
    }
    {   // 256 threads = 8 rays x 32 pairs: one (ray, h-pair) each
        const int rr  = t >> 5;
        const int k   = t & (NPAIR - 1);
        const int ray = blockIdx.x * RPB + rr;
        const float ox = ray_start[ray*3+0], oy = ray_start[ray*3+1], oz = ray_start[ray*3+2];
        const float dx = ray_dir[ray*3+0],  dy = ray_dir[ray*3+1],  dz = ray_dir[ray*3+2];
        const int h0 = 2*k, h1 = 2*k + 1;
        const float u0 = W1[h0], u1 = W1[HID + h0], u2 = W1[2*HID + h0];
        const float v0 = W1[h1], v1 = W1[HID + h1], v2 = W1[2*HID + h1];
        const float A0 = fmaf(u0, ox, fmaf(u1, oy, fmaf(u2, oz, b1[h0])));
        const float B0 = fmaf(u0, dx, fmaf(u1, dy, u2 * dz));
        const float A1 = fmaf(v0, ox, fmaf(v1, oy, fmaf(v2, oz, b1[h1])));
        const float B1 = fmaf(v0, dx, fmaf(v1, dy, v2 * dz));
        AB2 e; e.A = mk2(A0, A1); e.B = mk2(B0, B1);
        sAB[rr][k] = e;
    }
    __syncthreads();

    const int lane = t & 63;
    const int wave = t >> 6;
    const int hl   = lane & 31;                 // position within half-wave
    const int r    = wave * 2 + (lane >> 5);    // ray slot in block
    const int ray  = blockIdx.x * RPB + r;

    // per-ray view-dependent rgb bias (fp32, uniform across half-wave)
    const float dx = ray_dir[ray*3+0], dy = ray_dir[ray*3+1], dz = ray_dir[ray*3+2];
    const float dwr = fmaf(dx, W_dir[0], fmaf(dy, W_dir[3], fmaf(dz, W_dir[6], b_rgb[0])));
    const float dwg = fmaf(dx, W_dir[1], fmaf(dy, W_dir[4], fmaf(dz, W_dir[7], b_rgb[1])));
    const float dwb = fmaf(dx, W_dir[2], fmaf(dy, W_dir[5], fmaf(dz, W_dir[8], b_rgb[2])));

    // this thread owns samples SPT*hl .. SPT*hl+7 (contiguous)
    const size_t rbase = (size_t)ray * NS + (size_t)hl * SPT;
    const float4 dep0 = ((const float4*)(sampled_depth + rbase))[0];
    const float4 dep1 = ((const float4*)(sampled_depth + rbase))[1];
    const float4 dst0 = ((const float4*)(sampled_dists + rbase))[0];
    const float4 dst1 = ((const float4*)(sampled_dists + rbase))[1];
    const int4   vi0  = ((const int4*)(sampled_idx + rbase))[0];
    const int4   vi1  = ((const int4*)(sampled_idx + rbase))[1];

    const float dpt[SPT] = {dep0.x, dep0.y, dep0.z, dep0.w, dep1.x, dep1.y, dep1.z, dep1.w};
    const float dsv[SPT] = {dst0.x, dst0.y, dst0.z, dst0.w, dst1.x, dst1.y, dst1.z, dst1.w};
    const int   vid[SPT] = {vi0.x, vi0.y, vi0.z, vi0.w, vi1.x, vi1.y, vi1.z, vi1.w};

    f16x2 d2[SPT];
#pragma unroll
    for (int j = 0; j < SPT; ++j) d2[j] = mk2(dpt[j], dpt[j]);
    const f16x2 zero2 = mk2(0.f, 0.f);

    float sig[SPT] = {0,0,0,0,0,0,0,0};
    float cr[SPT]  = {0,0,0,0,0,0,0,0};
    float cg[SPT]  = {0,0,0,0,0,0,0,0};
    float cb[SPT]  = {0,0,0,0,0,0,0,0};

#pragma unroll 4
    for (int k = 0; k < NPAIR; ++k) {
        const W4  w  = sW[k];        // ds_read_b128, broadcast
        const AB2 ab = sAB[r][k];    // ds_read_b64, 2 addrs/wave
#pragma unroll
        for (int j = 0; j < SPT; ++j) {
            f16x2 hv = __builtin_elementwise_fma(ab.B, d2[j], ab.A);  // v_pk_fma_f16
            hv = __builtin_elementwise_max(hv, zero2);                // v_pk_max_f16
            sig[j] = fdot2(hv, w.ws, sig[j]);                         // v_dot2_f32_f16
            cr[j]  = fdot2(hv, w.wr, cr[j]);
            cg[j]  = fdot2(hv, w.wg, cg[j]);
            cb[j]  = fdot2(hv, w.wb, cb[j]);
        }
    }

    // free energy + thread-local inclusive scan (fp32 throughout)
    float c[SPT];
    float run = 0.f;
#pragma unroll
    for (int j = 0; j < SPT; ++j) {
        float f = fmaxf(sig[j], 0.f) * dsv[j] * 7.0f;
        if (vid[j] == -1) f = 0.f;
        run += f;
        c[j] = run;
    }

    // half-wave (width 32) exclusive scan of per-thread totals
    float tot = run;
#pragma unroll
    for (int off = 1; off < 32; off <<= 1) {
        const float v = __shfl_up(tot, off, 32);
        if (hl >= off) tot += v;
    }
    const float base = tot - run;

    // telescoped probs: p[j] = exp(-(base+c[j-1])) - exp(-(base+c[j]))
    float Eprev = __expf(-base);
    float prob[SPT];
    float s0 = 0.f, s1 = 0.f, s2 = 0.f, s3 = 0.f, s4 = 0.f;
#pragma unroll
    for (int j = 0; j < SPT; ++j) {
        const float Ej = __expf(-(base + c[j]));
        const float p  = Eprev - Ej;
        Eprev = Ej;
        prob[j] = p;
        const float rr = __builtin_amdgcn_rcpf(1.f + __expf(-(cr[j] + dwr)));
        const float gg = __builtin_amdgcn_rcpf(1.f + __expf(-(cg[j] + dwg)));
        const float bb = __builtin_amdgcn_rcpf(1.f + __expf(-(cb[j] + dwb)));
        s0 += p;
        s1 = fmaf(dpt[j], p, s1);
        s2 = fmaf(rr, p, s2);
        s3 = fmaf(gg, p, s3);
        s4 = fmaf(bb, p, s4);
    }

    // half-wave reduction of the 5 sums
#pragma unroll
    for (int off = 16; off >= 1; off >>= 1) {
        s0 += __shfl_xor(s0, off, 32);
        s1 += __shfl_xor(s1, off, 32);
        s2 += __shfl_xor(s2, off, 32);
        s3 += __shfl_xor(s3, off, 32);
        s4 += __shfl_xor(s4, off, 32);
    }

    float* orow = out + (size_t)ray * (NS + 5);
#pragma unroll
    for (int j = 0; j < SPT; ++j)
        orow[5 + SPT*hl + j] = prob[j];

    if (hl == 0) {
        orow[0] = s2;          // r
        orow[1] = s3;          // g
        orow[2] = s4;          // b
        orow[3] = s1;          // depth
        orow[4] = 1.f - s0;    // missed
    }
}

extern "C" void kernel_launch(void* const* d_in, const int* in_sizes, int n_in,
                              void* d_out, int out_size, void* d_ws, size_t ws_size,
                              hipStream_t stream)
{
    vr_kernel<<<NRAYS / RPB, 256, 0, stream>>>(
        (const float*)d_in[0],   // ray_start
        (const float*)d_in[1],   // ray_dir
        (const float*)d_in[2],   // sampled_depth
        (const float*)d_in[3],   // sampled_dists
        (const int*)  d_in[4],   // sampled_idx
        (const float*)d_in[5],   // W1
        (const float*)d_in[6],   // b1
        (const float*)d_in[7],   // w_sigma
        (const float*)d_in[8],   // W_rgb
        (const float*)d_in[9],   // W_dir
        (const float*)d_in[10],  // b_rgb
        (float*)d_out);
}